// Round 23
// baseline (1056.208 us; speedup 1.0000x reference)
//
#include <hip/hip_runtime.h>
#include <hip/hip_bf16.h>
#include <stdint.h>

// ---------------------------------------------------------------------------
// Threefry-2x32-20 + JAX partitionable bits (verified passing, rounds 10-22)
// ---------------------------------------------------------------------------
__device__ __forceinline__ uint32_t rotl32(uint32_t v, int s) {
    return (v << s) | (v >> (32 - s));
}

__device__ __forceinline__ void tf2x32(uint32_t k0, uint32_t k1,
                                       uint32_t x0, uint32_t x1,
                                       uint32_t& o0, uint32_t& o1) {
    uint32_t ks2 = k0 ^ k1 ^ 0x1BD11BDAu;
    x0 += k0; x1 += k1;
#define TFR(R0,R1,R2,R3) \
    x0 += x1; x1 = rotl32(x1, R0); x1 ^= x0; \
    x0 += x1; x1 = rotl32(x1, R1); x1 ^= x0; \
    x0 += x1; x1 = rotl32(x1, R2); x1 ^= x0; \
    x0 += x1; x1 = rotl32(x1, R3); x1 ^= x0;
    TFR(13,15,26,6)   x0 += k1;  x1 += ks2 + 1u;
    TFR(17,29,16,24)  x0 += ks2; x1 += k0  + 2u;
    TFR(13,15,26,6)   x0 += k0;  x1 += k1  + 3u;
    TFR(17,29,16,24)  x0 += k1;  x1 += ks2 + 4u;
    TFR(13,15,26,6)   x0 += ks2; x1 += k0  + 5u;
#undef TFR
    o0 = x0; o1 = x1;
}

__device__ __forceinline__ uint32_t pbits32(uint32_t k0, uint32_t k1, uint32_t ctr) {
    uint32_t o0, o1;
    tf2x32(k0, k1, 0u, ctr, o0, o1);
    return o0 ^ o1;
}

#define NROW 64
#define NCOL 2048
#define NFLAT 131072
#define SPLIT 392
#define C2 2.8853900817779268f    // 2/tau * log2(e)

__device__ __forceinline__ float gumbel_from_bits(uint32_t bits) {
    const float TINY = 1.17549435e-38f;
    float f = (float)(bits >> 9) * 1.1920928955078125e-7f;
    float u = fmaxf(TINY, f + TINY);
    return -logf(-logf(u));
}

// ---------------------------------------------------------------------------
// DPP wave64 sum (validated r14-r22)
// ---------------------------------------------------------------------------
template<int CTRL, int RM>
__device__ __forceinline__ float dpp_add(float s) {
    int x = __builtin_amdgcn_update_dpp(0, __builtin_bit_cast(int, s),
                                        CTRL, RM, 0xf, true);
    return s + __builtin_bit_cast(float, x);
}

__device__ __forceinline__ float wave_sum64(float v) {
    v = dpp_add<0x111, 0xf>(v);   // row_shr:1
    v = dpp_add<0x112, 0xf>(v);   // row_shr:2
    v = dpp_add<0x114, 0xf>(v);   // row_shr:4
    v = dpp_add<0x118, 0xf>(v);   // row_shr:8
    v = dpp_add<0x142, 0xa>(v);   // row_bcast:15
    v = dpp_add<0x143, 0xc>(v);   // row_bcast:31
    return __builtin_bit_cast(float,
        __builtin_amdgcn_readlane(__builtin_bit_cast(int, v), 63));
}

// ---------------------------------------------------------------------------
// keygen (partitionable foldlike split)
// ---------------------------------------------------------------------------
__global__ __launch_bounds__(256) void keygenF(uint32_t* __restrict__ kb) {
    int n = blockIdx.x * 256 + threadIdx.x;
    uint32_t o0, o1;
    tf2x32(0u, 42u, 0u, (uint32_t)n, o0, o1);
    kb[2 * n] = o0;
    kb[2 * n + 1] = o1;
}

// ---------------------------------------------------------------------------
// FFT real part -> x[64][2048]
// ---------------------------------------------------------------------------
__device__ __constant__ float c_ctab[8] = {
    1.0f, 0.70710678118654752f, 0.0f, -0.70710678118654752f,
   -1.0f, -0.70710678118654752f, 0.0f, 0.70710678118654752f
};

__global__ __launch_bounds__(256) void fft_x(const float* __restrict__ f,
                                             float* __restrict__ x) {
    int gid = blockIdx.x * 256 + threadIdx.x;
    int b = gid >> 10, i = gid & 1023;
    int c = i >> 6, h = (i >> 3) & 7, w = i & 7;
    const float* fb = f + ((b << 4) + c) * 64;
    float s = 0.0f;
#pragma unroll
    for (int hp = 0; hp < 8; ++hp) {
#pragma unroll
        for (int wp = 0; wp < 8; ++wp)
            s += fb[hp * 8 + wp] * c_ctab[(h * hp + w * wp) & 7];
    }
    x[b * NCOL + i] = s;
    x[b * NCOL + 1024 + i] = s;
}

// ---------------------------------------------------------------------------
// prep: fold BN1/BN2 + bias into per-k affine: y = relu(dot*s + o)
// ---------------------------------------------------------------------------
__global__ __launch_bounds__(256) void prep(
    const float* __restrict__ b1, const float* __restrict__ g1,
    const float* __restrict__ be1, const float* __restrict__ rm1, const float* __restrict__ rv1,
    const float* __restrict__ b2, const float* __restrict__ g2,
    const float* __restrict__ be2, const float* __restrict__ rm2, const float* __restrict__ rv2,
    float* __restrict__ s1, float* __restrict__ o1,
    float* __restrict__ s2, float* __restrict__ o2) {
    int i = blockIdx.x * 256 + threadIdx.x;     // [0,8192)
    const float eps = 1e-5f;
    float inv = 1.0f / sqrtf(rv1[i] + eps);
    float s = g1[i] * inv;
    s1[i] = s; o1[i] = (b1[i] - rm1[i]) * s + be1[i];
    inv = 1.0f / sqrtf(rv2[i] + eps);
    s = g2[i] * inv;
    s2[i] = s; o2[i] = (b2[i] - rm2[i]) * s + be2[i];
}

// ---------------------------------------------------------------------------
// fp32 TN GEMM, k-split — r13 core (44 VGPR, proven 155-160 us at L2)
// ---------------------------------------------------------------------------
template<bool AFF>
__global__ __launch_bounds__(256)
void gemm_ks(const float* __restrict__ A,
             const float* __restrict__ sA, const float* __restrict__ oA,
             const float* __restrict__ B, float* __restrict__ Cpart,
             int K, int Kc, int N) {
    __shared__ float As[32][68];
    __shared__ float Bs[32][132];
    const int t = threadIdx.x;
    const int n0 = blockIdx.x * 128;
    const int k0 = blockIdx.y * Kc;
    const int tm = t >> 4, tn = t & 15;

    float acc[4][8];
#pragma unroll
    for (int i = 0; i < 4; ++i)
#pragma unroll
        for (int j = 0; j < 8; ++j) acc[i][j] = 0.0f;

    for (int kt = k0; kt < k0 + Kc; kt += 32) {
#pragma unroll
        for (int h = 0; h < 2; ++h) {
            int idx = h * 1024 + t * 4;
            int am = idx >> 5, ak = idx & 31;
            size_t go = (size_t)am * K + kt + ak;
            float4 v = *(const float4*)(A + go);
            if (AFF) {
                float4 s = *(const float4*)(sA + kt + ak);
                float4 o = *(const float4*)(oA + kt + ak);
                v.x = fmaxf(v.x * s.x + o.x, 0.0f);
                v.y = fmaxf(v.y * s.y + o.y, 0.0f);
                v.z = fmaxf(v.z * s.z + o.z, 0.0f);
                v.w = fmaxf(v.w * s.w + o.w, 0.0f);
            }
            As[ak + 0][am] = v.x; As[ak + 1][am] = v.y;
            As[ak + 2][am] = v.z; As[ak + 3][am] = v.w;
        }
#pragma unroll
        for (int h = 0; h < 4; ++h) {
            int idx = h * 1024 + t * 4;
            int bn = idx >> 5, bk = idx & 31;
            float4 v = *(const float4*)(B + (size_t)(n0 + bn) * K + kt + bk);
            Bs[bk + 0][bn] = v.x; Bs[bk + 1][bn] = v.y;
            Bs[bk + 2][bn] = v.z; Bs[bk + 3][bn] = v.w;
        }
        __syncthreads();
#pragma unroll 8
        for (int kk = 0; kk < 32; ++kk) {
            float4 av = *(const float4*)&As[kk][tm << 2];
            float4 b0 = *(const float4*)&Bs[kk][tn << 3];
            float4 b1 = *(const float4*)&Bs[kk][(tn << 3) + 4];
            float a4[4] = {av.x, av.y, av.z, av.w};
            float b8[8] = {b0.x, b0.y, b0.z, b0.w, b1.x, b1.y, b1.z, b1.w};
#pragma unroll
            for (int i = 0; i < 4; ++i)
#pragma unroll
                for (int j = 0; j < 8; ++j)
                    acc[i][j] = fmaf(a4[i], b8[j], acc[i][j]);
        }
        __syncthreads();
    }
#pragma unroll
    for (int i = 0; i < 4; ++i) {
        size_t co = (size_t)blockIdx.y * ((size_t)64 * N)
                  + (size_t)((tm << 2) + i) * N + n0 + (tn << 3);
        float4 v0 = {acc[i][0], acc[i][1], acc[i][2], acc[i][3]};
        float4 v1 = {acc[i][4], acc[i][5], acc[i][6], acc[i][7]};
        *(float4*)(Cpart + co) = v0;
        *(float4*)(Cpart + co + 4) = v1;
    }
}

// ---------------------------------------------------------------------------
// combineP / combine3
// ---------------------------------------------------------------------------
__global__ __launch_bounds__(256) void combineP(const float* __restrict__ parts,
                                                float* __restrict__ dst,
                                                int P, int total) {
    int gid = blockIdx.x * 256 + threadIdx.x;
    if (gid >= total) return;
    float s = 0.0f;
    for (int p = 0; p < P; ++p) s += parts[(size_t)p * total + gid];
    dst[gid] = s;
}

__global__ __launch_bounds__(256) void combine3(const float* __restrict__ parts,
                                                const float* __restrict__ b3,
                                                const float* __restrict__ rm3,
                                                const float* __restrict__ rv3,
                                                float* __restrict__ mstate, int P) {
    int gid = blockIdx.x * 256 + threadIdx.x;   // [0,131072)
    int c = gid & 2047;
    float v = 0.0f;
    for (int p = 0; p < P; ++p) v += parts[(size_t)p * NFLAT + gid];
    mstate[gid] = (v + b3[c] - rm3[c]) / sqrtf(rv3[c] + 1e-5f);
}

// ---------------------------------------------------------------------------
// standalone hash (prologue)
// ---------------------------------------------------------------------------
__global__ __launch_bounds__(1024)
void hash_chunk(const uint32_t* __restrict__ kb, float* __restrict__ gbuf,
                int t0, int Tc) {
    size_t total = (size_t)Tc * NFLAT;
    for (size_t idx = (size_t)blockIdx.x * 1024 + threadIdx.x; idx < total;
         idx += (size_t)gridDim.x * 1024) {
        int tt = (int)(idx >> 17);
        int j  = (int)(idx & (NFLAT - 1));
        int tg = t0 + tt;
        uint32_t k0 = kb[2 * tg], k1 = kb[2 * tg + 1];
        gbuf[idx] = gumbel_from_bits(pbits32(k0, k1, (uint32_t)j)) * C2;
    }
}

// ---------------------------------------------------------------------------
// scan_fused: r22 structure, but the per-iteration barrier is a RAW
// s_barrier preceded by lgkmcnt(0) ONLY (no vmcnt drain), so the 8-deep
// register FIFO of gumbel prefetches stays in flight across iterations.
// LDS red[2][16] double-buffer makes the single-barrier scheme race-free.
// blocks 0..63: scan row r; blocks 64..255: grid-stride hash -> hdst.
// ---------------------------------------------------------------------------
__global__ __launch_bounds__(1024)
void scan_fused(float* __restrict__ mstate, float* __restrict__ zstate,
                const float* __restrict__ gscan,
                float* __restrict__ hdst, int ht0, int hcnt,
                const uint32_t* __restrict__ kb,
                int t0, int Tc, int last, float* __restrict__ out) {
    const int tid = threadIdx.x;

    if (blockIdx.x >= 64) {
        if (hcnt <= 0) return;
        int hb = blockIdx.x - 64;              // 0..191
        size_t total = (size_t)hcnt * NFLAT;
        for (size_t idx = (size_t)hb * 1024 + tid; idx < total;
             idx += (size_t)192 * 1024) {
            int tt = (int)(idx >> 17);
            int j  = (int)(idx & (NFLAT - 1));
            int tg = ht0 + tt;
            uint32_t k0 = kb[2 * tg], k1 = kb[2 * tg + 1];
            hdst[idx] = gumbel_from_bits(pbits32(k0, k1, (uint32_t)j)) * C2;
        }
        return;
    }

    __shared__ __align__(16) float red[2][16];
    const int r = blockIdx.x;
    const int c0 = tid, c1 = tid + 1024;
    const int base = r * NCOL;
    float m0 = mstate[base + c0], m1 = mstate[base + c1];
    float z0, z1;
    if (t0 == 0) { z0 = 0.0f; z1 = 0.0f; }
    else         { z0 = zstate[base + c0]; z1 = zstate[base + c1]; }
    const int lane = tid & 63, wid = tid >> 6;

    // 8-deep prefetch FIFO (Tc is a multiple of 8, >= 8)
    float g0f[8], g1f[8];
#pragma unroll
    for (int d = 0; d < 8; ++d) {
        size_t ao = (size_t)d * NFLAT + base;
        g0f[d] = gscan[ao + c0];
        g1f[d] = gscan[ao + c1];
    }

    for (int tb = 0; tb < Tc; tb += 8) {
#pragma unroll
        for (int ph = 0; ph < 8; ++ph) {
            int tt = tb + ph;
            float cg0 = g0f[ph], cg1 = g1f[ph];
            if (tt + 8 < Tc) {                 // refill slot for iter tt+8
                size_t ao = (size_t)(tt + 8) * NFLAT + base;
                g0f[ph] = gscan[ao + c0];
                g1f[ph] = gscan[ao + c1];
            }
            float p0 = exp2f(fmaf(m0, C2, cg0));
            float p1 = exp2f(fmaf(m1, C2, cg1));
            float ws = wave_sum64(p0 + p1);
            if (lane == 0) red[tt & 1][wid] = ws;
            // drain LDS only; global prefetches stay outstanding
            asm volatile("s_waitcnt lgkmcnt(0)" ::: "memory");
            __builtin_amdgcn_s_barrier();
            __builtin_amdgcn_sched_barrier(0);
            float S;
            {
                const float4* r4 = (const float4*)&red[tt & 1][0];
                float4 v0 = r4[0], v1 = r4[1], v2 = r4[2], v3 = r4[3];
                S = ((v0.x + v0.y) + (v0.z + v0.w)) + ((v1.x + v1.y) + (v1.z + v1.w))
                  + ((v2.x + v2.y) + (v2.z + v2.w)) + ((v3.x + v3.y) + (v3.z + v3.w));
            }
            float rs = __builtin_amdgcn_rcpf(S);
            m0 = p0 * rs; m1 = p1 * rs;
            z0 = fmaxf(z0, m0); z1 = fmaxf(z1, m1);
        }
    }
    mstate[base + c0] = m0; mstate[base + c1] = m1;
    zstate[base + c0] = z0; zstate[base + c1] = z1;
    if (last) {
        if (c0 < SPLIT) out[r * SPLIT + c0] = z0;
        else out[64 * SPLIT + r * (NCOL - SPLIT) + (c0 - SPLIT)] = z0;
        out[64 * SPLIT + r * (NCOL - SPLIT) + (c1 - SPLIT)] = z1;
    }
}

// ---------------------------------------------------------------------------
// inline-hash fallback (ws too small for any gbuf)
// ---------------------------------------------------------------------------
__global__ __launch_bounds__(1024)
void scan_inline(const float* __restrict__ mstate, const uint32_t* __restrict__ kb,
                 float* __restrict__ out) {
    const int r = blockIdx.x;
    const int tid = threadIdx.x;
    const int c0 = tid, c1 = tid + 1024;
    const int base = r * NCOL;
    float m0 = mstate[base + c0], m1 = mstate[base + c1];
    float z0 = 0.0f, z1 = 0.0f;
    __shared__ __align__(16) float red[2][16];
    const int lane = tid & 63, wid = tid >> 6;

    for (int t = 0; t < 1024; ++t) {
        uint32_t k0 = kb[2 * t], k1 = kb[2 * t + 1];
        float g0 = gumbel_from_bits(pbits32(k0, k1, (uint32_t)(base + c0)));
        float g1 = gumbel_from_bits(pbits32(k0, k1, (uint32_t)(base + c1)));
        float p0 = exp2f((m0 + g0) * C2);
        float p1 = exp2f((m1 + g1) * C2);
        float ws = wave_sum64(p0 + p1);
        if (lane == 0) red[t & 1][wid] = ws;
        __syncthreads();
        float S;
        {
            const float4* r4 = (const float4*)&red[t & 1][0];
            float4 v0 = r4[0], v1 = r4[1], v2 = r4[2], v3 = r4[3];
            S = ((v0.x + v0.y) + (v0.z + v0.w)) + ((v1.x + v1.y) + (v1.z + v1.w))
              + ((v2.x + v2.y) + (v2.z + v2.w)) + ((v3.x + v3.y) + (v3.z + v3.w));
        }
        float rs = __builtin_amdgcn_rcpf(S);
        m0 = p0 * rs; m1 = p1 * rs;
        z0 = fmaxf(z0, m0); z1 = fmaxf(z1, m1);
    }
    if (c0 < SPLIT) out[r * SPLIT + c0] = z0;
    else out[64 * SPLIT + r * (NCOL - SPLIT) + (c0 - SPLIT)] = z0;
    out[64 * SPLIT + r * (NCOL - SPLIT) + (c1 - SPLIT)] = z1;
}

// ---------------------------------------------------------------------------
// host
// ---------------------------------------------------------------------------
extern "C" void kernel_launch(void* const* d_in, const int* in_sizes, int n_in,
                              void* d_out, int out_size, void* d_ws, size_t ws_size,
                              hipStream_t stream) {
    const float* f   = (const float*)d_in[0];
    const float* W1  = (const float*)d_in[1];
    const float* b1  = (const float*)d_in[2];
    const float* g1  = (const float*)d_in[3];
    const float* be1 = (const float*)d_in[4];
    const float* rm1 = (const float*)d_in[5];
    const float* rv1 = (const float*)d_in[6];
    const float* W2  = (const float*)d_in[7];
    const float* b2  = (const float*)d_in[8];
    const float* g2  = (const float*)d_in[9];
    const float* be2 = (const float*)d_in[10];
    const float* rm2 = (const float*)d_in[11];
    const float* rv2 = (const float*)d_in[12];
    const float* W3  = (const float*)d_in[13];
    const float* b3  = (const float*)d_in[14];
    const float* rm3 = (const float*)d_in[15];
    const float* rv3 = (const float*)d_in[16];
    float* out = (float*)d_out;               // reference output dtype: float32

    float* ws = (float*)d_ws;
    size_t off = 0;
    auto alloc = [&](size_t n) { float* p = ws + off; off += n; return p; };

    uint32_t* keybuf = (uint32_t*)alloc(2048);
    float* s1 = alloc(8192); float* o1 = alloc(8192);
    float* s2 = alloc(8192); float* o2 = alloc(8192);
    float* x      = alloc(64 * 2048);
    float* h1     = alloc((size_t)64 * 8192);
    float* h2     = alloc((size_t)64 * 8192);
    float* mstate = alloc(NFLAT);
    float* zstate = alloc(NFLAT);
    size_t fixed = off;
    float* pbuf = ws + fixed;
    size_t region = (ws_size / 4 > fixed) ? (ws_size / 4 - fixed) : 0;

    const size_t HN = (size_t)64 * 8192;      // 524288
    const size_t GALL = (size_t)1024 * NFLAT; // 512 MiB of floats

    keygenF<<<dim3(4), 256, 0, stream>>>(keybuf);
    prep<<<dim3(32), 256, 0, stream>>>(b1, g1, be1, rm1, rv1,
                                       b2, g2, be2, rm2, rv2,
                                       s1, o1, s2, o2);
    fft_x<<<dim3(256), 256, 0, stream>>>(f, x);

    if (region >= GALL + 16 * HN) {
        // ============== BIG path ==========================================
        float* gbufAll = pbuf;
        float* parts   = pbuf + GALL;

        gemm_ks<false><<<dim3(64, 8), 256, 0, stream>>>(
            x, nullptr, nullptr, W1, parts, 2048, 256, 8192);
        combineP<<<dim3(2048), 256, 0, stream>>>(parts, h1, 8, (int)HN);
        gemm_ks<true><<<dim3(64, 16), 256, 0, stream>>>(
            h1, s1, o1, W2, parts, 8192, 512, 8192);
        combineP<<<dim3(2048), 256, 0, stream>>>(parts, h2, 16, (int)HN);
        gemm_ks<true><<<dim3(16, 16), 256, 0, stream>>>(
            h2, s2, o2, W3, parts, 8192, 512, 2048);
        combine3<<<dim3(512), 256, 0, stream>>>(parts, b3, rm3, rv3, mstate, 16);

        hash_chunk<<<dim3(256), 1024, 0, stream>>>(keybuf, gbufAll, 0, 128);
        for (int ch = 0; ch < 8; ++ch) {
            int hstart = (ch + 1) * 128;
            int hcnt = (hstart < 1024) ? 128 : 0;
            scan_fused<<<dim3(256), 1024, 0, stream>>>(
                mstate, zstate, gbufAll + (size_t)ch * 128 * NFLAT,
                gbufAll + (size_t)hstart * NFLAT, hstart, hcnt, keybuf,
                ch * 128, 128, (ch == 7) ? 1 : 0, out);
        }
    } else {
        // ============== SMALL path ========================================
        int KS1 = (region >= 8 * HN) ? 8 : (region >= 4 * HN) ? 4 :
                  (region >= 2 * HN) ? 2 : 1;
        int KS2 = (region >= 16 * HN) ? 16 : (region >= 8 * HN) ? 8 :
                  (region >= 4 * HN) ? 4 : (region >= 2 * HN) ? 2 : 1;
        int KS3 = (region >= 16 * (size_t)NFLAT) ? 16 :
                  (region >= 8 * (size_t)NFLAT) ? 8 :
                  (region >= 4 * (size_t)NFLAT) ? 4 :
                  (region >= 2 * (size_t)NFLAT) ? 2 : 1;
        int Tc = 0;
        const int cands[5] = {128, 64, 32, 16, 8};
        for (int ci = 0; ci < 5; ++ci)
            if (2 * (size_t)cands[ci] * NFLAT <= region) { Tc = cands[ci]; break; }

        gemm_ks<false><<<dim3(64, KS1), 256, 0, stream>>>(
            x, nullptr, nullptr, W1, (KS1 > 1) ? pbuf : h1, 2048, 2048 / KS1, 8192);
        if (KS1 > 1) combineP<<<dim3(2048), 256, 0, stream>>>(pbuf, h1, KS1, (int)HN);

        gemm_ks<true><<<dim3(64, KS2), 256, 0, stream>>>(
            h1, s1, o1, W2, (KS2 > 1) ? pbuf : h2, 8192, 8192 / KS2, 8192);
        if (KS2 > 1) combineP<<<dim3(2048), 256, 0, stream>>>(pbuf, h2, KS2, (int)HN);

        if (KS3 > 1) {
            gemm_ks<true><<<dim3(16, KS3), 256, 0, stream>>>(
                h2, s2, o2, W3, pbuf, 8192, 8192 / KS3, 2048);
            combine3<<<dim3(512), 256, 0, stream>>>(pbuf, b3, rm3, rv3, mstate, KS3);
        } else {
            gemm_ks<true><<<dim3(16, 1), 256, 0, stream>>>(
                h2, s2, o2, W3, h1, 8192, 8192, 2048);
            combine3<<<dim3(512), 256, 0, stream>>>(h1, b3, rm3, rv3, mstate, 1);
        }

        if (Tc > 0) {
            float* gbuf0 = pbuf;
            float* gbuf1 = pbuf + (size_t)Tc * NFLAT;
            int NC = 1024 / Tc;
            hash_chunk<<<dim3(256), 1024, 0, stream>>>(keybuf, gbuf0, 0, Tc);
            for (int ch = 0; ch < NC; ++ch) {
                float* ga = (ch & 1) ? gbuf1 : gbuf0;
                float* gb = (ch & 1) ? gbuf0 : gbuf1;
                int last = (ch == NC - 1) ? 1 : 0;
                scan_fused<<<dim3(256), 1024, 0, stream>>>(
                    mstate, zstate, ga, gb, (ch + 1) * Tc, last ? 0 : Tc,
                    keybuf, ch * Tc, Tc, last, out);
            }
        } else {
            scan_inline<<<dim3(64), 1024, 0, stream>>>(mstate, keybuf, out);
        }
    }
}

// Round 24
// 878.670 us; speedup vs baseline: 1.2021x; 1.2021x over previous
//
#include <hip/hip_runtime.h>
#include <hip/hip_bf16.h>
#include <stdint.h>

// ---------------------------------------------------------------------------
// Threefry-2x32-20 + JAX partitionable bits (verified passing, rounds 10-23)
// ---------------------------------------------------------------------------
__device__ __forceinline__ uint32_t rotl32(uint32_t v, int s) {
    return (v << s) | (v >> (32 - s));
}

__device__ __forceinline__ void tf2x32(uint32_t k0, uint32_t k1,
                                       uint32_t x0, uint32_t x1,
                                       uint32_t& o0, uint32_t& o1) {
    uint32_t ks2 = k0 ^ k1 ^ 0x1BD11BDAu;
    x0 += k0; x1 += k1;
#define TFR(R0,R1,R2,R3) \
    x0 += x1; x1 = rotl32(x1, R0); x1 ^= x0; \
    x0 += x1; x1 = rotl32(x1, R1); x1 ^= x0; \
    x0 += x1; x1 = rotl32(x1, R2); x1 ^= x0; \
    x0 += x1; x1 = rotl32(x1, R3); x1 ^= x0;
    TFR(13,15,26,6)   x0 += k1;  x1 += ks2 + 1u;
    TFR(17,29,16,24)  x0 += ks2; x1 += k0  + 2u;
    TFR(13,15,26,6)   x0 += k0;  x1 += k1  + 3u;
    TFR(17,29,16,24)  x0 += k1;  x1 += ks2 + 4u;
    TFR(13,15,26,6)   x0 += ks2; x1 += k0  + 5u;
#undef TFR
    o0 = x0; o1 = x1;
}

__device__ __forceinline__ uint32_t pbits32(uint32_t k0, uint32_t k1, uint32_t ctr) {
    uint32_t o0, o1;
    tf2x32(k0, k1, 0u, ctr, o0, o1);
    return o0 ^ o1;
}

#define NROW 64
#define NCOL 2048
#define NFLAT 131072
#define SPLIT 392
#define C2 2.8853900817779268f    // 2/tau * log2(e)

__device__ __forceinline__ float gumbel_from_bits(uint32_t bits) {
    const float TINY = 1.17549435e-38f;
    float f = (float)(bits >> 9) * 1.1920928955078125e-7f;
    float u = fmaxf(TINY, f + TINY);
    return -logf(-logf(u));
}

// ---------------------------------------------------------------------------
// DPP wave64 sum (validated r14-r23)
// ---------------------------------------------------------------------------
template<int CTRL, int RM>
__device__ __forceinline__ float dpp_add(float s) {
    int x = __builtin_amdgcn_update_dpp(0, __builtin_bit_cast(int, s),
                                        CTRL, RM, 0xf, true);
    return s + __builtin_bit_cast(float, x);
}

__device__ __forceinline__ float wave_sum64(float v) {
    v = dpp_add<0x111, 0xf>(v);   // row_shr:1
    v = dpp_add<0x112, 0xf>(v);   // row_shr:2
    v = dpp_add<0x114, 0xf>(v);   // row_shr:4
    v = dpp_add<0x118, 0xf>(v);   // row_shr:8
    v = dpp_add<0x142, 0xa>(v);   // row_bcast:15
    v = dpp_add<0x143, 0xc>(v);   // row_bcast:31
    return __builtin_bit_cast(float,
        __builtin_amdgcn_readlane(__builtin_bit_cast(int, v), 63));
}

// ---------------------------------------------------------------------------
// keygen (partitionable foldlike split)
// ---------------------------------------------------------------------------
__global__ __launch_bounds__(256) void keygenF(uint32_t* __restrict__ kb) {
    int n = blockIdx.x * 256 + threadIdx.x;
    uint32_t o0, o1;
    tf2x32(0u, 42u, 0u, (uint32_t)n, o0, o1);
    kb[2 * n] = o0;
    kb[2 * n + 1] = o1;
}

// ---------------------------------------------------------------------------
// FFT real part -> x[64][2048]
// ---------------------------------------------------------------------------
__device__ __constant__ float c_ctab[8] = {
    1.0f, 0.70710678118654752f, 0.0f, -0.70710678118654752f,
   -1.0f, -0.70710678118654752f, 0.0f, 0.70710678118654752f
};

__global__ __launch_bounds__(256) void fft_x(const float* __restrict__ f,
                                             float* __restrict__ x) {
    int gid = blockIdx.x * 256 + threadIdx.x;
    int b = gid >> 10, i = gid & 1023;
    int c = i >> 6, h = (i >> 3) & 7, w = i & 7;
    const float* fb = f + ((b << 4) + c) * 64;
    float s = 0.0f;
#pragma unroll
    for (int hp = 0; hp < 8; ++hp) {
#pragma unroll
        for (int wp = 0; wp < 8; ++wp)
            s += fb[hp * 8 + wp] * c_ctab[(h * hp + w * wp) & 7];
    }
    x[b * NCOL + i] = s;
    x[b * NCOL + 1024 + i] = s;
}

// ---------------------------------------------------------------------------
// prep: fold BN1/BN2 + bias into per-k affine: y = relu(dot*s + o)
// ---------------------------------------------------------------------------
__global__ __launch_bounds__(256) void prep(
    const float* __restrict__ b1, const float* __restrict__ g1,
    const float* __restrict__ be1, const float* __restrict__ rm1, const float* __restrict__ rv1,
    const float* __restrict__ b2, const float* __restrict__ g2,
    const float* __restrict__ be2, const float* __restrict__ rm2, const float* __restrict__ rv2,
    float* __restrict__ s1, float* __restrict__ o1,
    float* __restrict__ s2, float* __restrict__ o2) {
    int i = blockIdx.x * 256 + threadIdx.x;     // [0,8192)
    const float eps = 1e-5f;
    float inv = 1.0f / sqrtf(rv1[i] + eps);
    float s = g1[i] * inv;
    s1[i] = s; o1[i] = (b1[i] - rm1[i]) * s + be1[i];
    inv = 1.0f / sqrtf(rv2[i] + eps);
    s = g2[i] * inv;
    s2[i] = s; o2[i] = (b2[i] - rm2[i]) * s + be2[i];
}

// ---------------------------------------------------------------------------
// fp32 TN GEMM, k-split — r13 core (44 VGPR, proven 155-160 us at L2)
// ---------------------------------------------------------------------------
template<bool AFF>
__global__ __launch_bounds__(256)
void gemm_ks(const float* __restrict__ A,
             const float* __restrict__ sA, const float* __restrict__ oA,
             const float* __restrict__ B, float* __restrict__ Cpart,
             int K, int Kc, int N) {
    __shared__ float As[32][68];
    __shared__ float Bs[32][132];
    const int t = threadIdx.x;
    const int n0 = blockIdx.x * 128;
    const int k0 = blockIdx.y * Kc;
    const int tm = t >> 4, tn = t & 15;

    float acc[4][8];
#pragma unroll
    for (int i = 0; i < 4; ++i)
#pragma unroll
        for (int j = 0; j < 8; ++j) acc[i][j] = 0.0f;

    for (int kt = k0; kt < k0 + Kc; kt += 32) {
#pragma unroll
        for (int h = 0; h < 2; ++h) {
            int idx = h * 1024 + t * 4;
            int am = idx >> 5, ak = idx & 31;
            size_t go = (size_t)am * K + kt + ak;
            float4 v = *(const float4*)(A + go);
            if (AFF) {
                float4 s = *(const float4*)(sA + kt + ak);
                float4 o = *(const float4*)(oA + kt + ak);
                v.x = fmaxf(v.x * s.x + o.x, 0.0f);
                v.y = fmaxf(v.y * s.y + o.y, 0.0f);
                v.z = fmaxf(v.z * s.z + o.z, 0.0f);
                v.w = fmaxf(v.w * s.w + o.w, 0.0f);
            }
            As[ak + 0][am] = v.x; As[ak + 1][am] = v.y;
            As[ak + 2][am] = v.z; As[ak + 3][am] = v.w;
        }
#pragma unroll
        for (int h = 0; h < 4; ++h) {
            int idx = h * 1024 + t * 4;
            int bn = idx >> 5, bk = idx & 31;
            float4 v = *(const float4*)(B + (size_t)(n0 + bn) * K + kt + bk);
            Bs[bk + 0][bn] = v.x; Bs[bk + 1][bn] = v.y;
            Bs[bk + 2][bn] = v.z; Bs[bk + 3][bn] = v.w;
        }
        __syncthreads();
#pragma unroll 8
        for (int kk = 0; kk < 32; ++kk) {
            float4 av = *(const float4*)&As[kk][tm << 2];
            float4 b0 = *(const float4*)&Bs[kk][tn << 3];
            float4 b1 = *(const float4*)&Bs[kk][(tn << 3) + 4];
            float a4[4] = {av.x, av.y, av.z, av.w};
            float b8[8] = {b0.x, b0.y, b0.z, b0.w, b1.x, b1.y, b1.z, b1.w};
#pragma unroll
            for (int i = 0; i < 4; ++i)
#pragma unroll
                for (int j = 0; j < 8; ++j)
                    acc[i][j] = fmaf(a4[i], b8[j], acc[i][j]);
        }
        __syncthreads();
    }
#pragma unroll
    for (int i = 0; i < 4; ++i) {
        size_t co = (size_t)blockIdx.y * ((size_t)64 * N)
                  + (size_t)((tm << 2) + i) * N + n0 + (tn << 3);
        float4 v0 = {acc[i][0], acc[i][1], acc[i][2], acc[i][3]};
        float4 v1 = {acc[i][4], acc[i][5], acc[i][6], acc[i][7]};
        *(float4*)(Cpart + co) = v0;
        *(float4*)(Cpart + co + 4) = v1;
    }
}

// ---------------------------------------------------------------------------
// combineP / combine3
// ---------------------------------------------------------------------------
__global__ __launch_bounds__(256) void combineP(const float* __restrict__ parts,
                                                float* __restrict__ dst,
                                                int P, int total) {
    int gid = blockIdx.x * 256 + threadIdx.x;
    if (gid >= total) return;
    float s = 0.0f;
    for (int p = 0; p < P; ++p) s += parts[(size_t)p * total + gid];
    dst[gid] = s;
}

__global__ __launch_bounds__(256) void combine3(const float* __restrict__ parts,
                                                const float* __restrict__ b3,
                                                const float* __restrict__ rm3,
                                                const float* __restrict__ rv3,
                                                float* __restrict__ mstate, int P) {
    int gid = blockIdx.x * 256 + threadIdx.x;   // [0,131072)
    int c = gid & 2047;
    float v = 0.0f;
    for (int p = 0; p < P; ++p) v += parts[(size_t)p * NFLAT + gid];
    mstate[gid] = (v + b3[c] - rm3[c]) / sqrtf(rv3[c] + 1e-5f);
}

// ---------------------------------------------------------------------------
// standalone hash (prologue)
// ---------------------------------------------------------------------------
__global__ __launch_bounds__(1024)
void hash_chunk(const uint32_t* __restrict__ kb, float* __restrict__ gbuf,
                int t0, int Tc) {
    size_t total = (size_t)Tc * NFLAT;
    for (size_t idx = (size_t)blockIdx.x * 1024 + threadIdx.x; idx < total;
         idx += (size_t)gridDim.x * 1024) {
        int tt = (int)(idx >> 17);
        int j  = (int)(idx & (NFLAT - 1));
        int tg = t0 + tt;
        uint32_t k0 = kb[2 * tg], k1 = kb[2 * tg + 1];
        gbuf[idx] = gumbel_from_bits(pbits32(k0, k1, (uint32_t)j)) * C2;
    }
}

// ---------------------------------------------------------------------------
// scan_fused (r22 base + BATCH-16 prefetch): per 16-iteration batch, all 32
// gumbel loads issue up front; the first barrier's vmcnt(0) drain absorbs
// the full memory latency ONCE, and the remaining 15 barriers have no
// outstanding vmem -> no drain. Plain __syncthreads throughout.
// blocks 0..63: scan row r; blocks 64..255: grid-stride hash -> hdst.
// ---------------------------------------------------------------------------
__global__ __launch_bounds__(1024)
void scan_fused(float* __restrict__ mstate, float* __restrict__ zstate,
                const float* __restrict__ gscan,
                float* __restrict__ hdst, int ht0, int hcnt,
                const uint32_t* __restrict__ kb,
                int t0, int Tc, int last, float* __restrict__ out) {
    const int tid = threadIdx.x;

    if (blockIdx.x >= 64) {
        if (hcnt <= 0) return;
        int hb = blockIdx.x - 64;              // 0..191
        size_t total = (size_t)hcnt * NFLAT;
        for (size_t idx = (size_t)hb * 1024 + tid; idx < total;
             idx += (size_t)192 * 1024) {
            int tt = (int)(idx >> 17);
            int j  = (int)(idx & (NFLAT - 1));
            int tg = ht0 + tt;
            uint32_t k0 = kb[2 * tg], k1 = kb[2 * tg + 1];
            hdst[idx] = gumbel_from_bits(pbits32(k0, k1, (uint32_t)j)) * C2;
        }
        return;
    }

    __shared__ __align__(16) float red[2][16];
    const int r = blockIdx.x;
    const int c0 = tid, c1 = tid + 1024;
    const int base = r * NCOL;
    float m0 = mstate[base + c0], m1 = mstate[base + c1];
    float z0, z1;
    if (t0 == 0) { z0 = 0.0f; z1 = 0.0f; }
    else         { z0 = zstate[base + c0]; z1 = zstate[base + c1]; }
    const int lane = tid & 63, wid = tid >> 6;

    if ((Tc & 15) == 0) {
        // ---- batched path: 16 iterations per batch ----
        float gb0[16], gb1[16];
        for (int tb = 0; tb < Tc; tb += 16) {
            // issue ALL batch loads up front (one drain at first barrier)
#pragma unroll
            for (int d = 0; d < 16; ++d) {
                size_t ao = (size_t)(tb + d) * NFLAT + base;
                gb0[d] = gscan[ao + c0];
                gb1[d] = gscan[ao + c1];
            }
#pragma unroll
            for (int ph = 0; ph < 16; ++ph) {
                int tt = tb + ph;
                float p0 = exp2f(fmaf(m0, C2, gb0[ph]));
                float p1 = exp2f(fmaf(m1, C2, gb1[ph]));
                float ws = wave_sum64(p0 + p1);
                if (lane == 0) red[tt & 1][wid] = ws;
                __syncthreads();
                float S;
                {
                    const float4* r4 = (const float4*)&red[tt & 1][0];
                    float4 v0 = r4[0], v1 = r4[1], v2 = r4[2], v3 = r4[3];
                    S = ((v0.x + v0.y) + (v0.z + v0.w)) + ((v1.x + v1.y) + (v1.z + v1.w))
                      + ((v2.x + v2.y) + (v2.z + v2.w)) + ((v3.x + v3.y) + (v3.z + v3.w));
                }
                float rs = __builtin_amdgcn_rcpf(S);
                m0 = p0 * rs; m1 = p1 * rs;
                z0 = fmaxf(z0, m0); z1 = fmaxf(z1, m1);
            }
        }
    } else {
        // ---- fallback: r22 single-prefetch loop ----
        float g0 = gscan[base + c0];
        float g1 = gscan[base + c1];
        for (int tt = 0; tt < Tc; ++tt) {
            float cg0 = g0, cg1 = g1;
            if (tt + 1 < Tc) {
                size_t ao = (size_t)(tt + 1) * NFLAT + base;
                g0 = gscan[ao + c0];
                g1 = gscan[ao + c1];
            }
            float p0 = exp2f(fmaf(m0, C2, cg0));
            float p1 = exp2f(fmaf(m1, C2, cg1));
            float ws = wave_sum64(p0 + p1);
            if (lane == 0) red[tt & 1][wid] = ws;
            __syncthreads();
            float S;
            {
                const float4* r4 = (const float4*)&red[tt & 1][0];
                float4 v0 = r4[0], v1 = r4[1], v2 = r4[2], v3 = r4[3];
                S = ((v0.x + v0.y) + (v0.z + v0.w)) + ((v1.x + v1.y) + (v1.z + v1.w))
                  + ((v2.x + v2.y) + (v2.z + v2.w)) + ((v3.x + v3.y) + (v3.z + v3.w));
            }
            float rs = __builtin_amdgcn_rcpf(S);
            m0 = p0 * rs; m1 = p1 * rs;
            z0 = fmaxf(z0, m0); z1 = fmaxf(z1, m1);
        }
    }

    mstate[base + c0] = m0; mstate[base + c1] = m1;
    zstate[base + c0] = z0; zstate[base + c1] = z1;
    if (last) {
        if (c0 < SPLIT) out[r * SPLIT + c0] = z0;
        else out[64 * SPLIT + r * (NCOL - SPLIT) + (c0 - SPLIT)] = z0;
        out[64 * SPLIT + r * (NCOL - SPLIT) + (c1 - SPLIT)] = z1;
    }
}

// ---------------------------------------------------------------------------
// inline-hash fallback (ws too small for any gbuf)
// ---------------------------------------------------------------------------
__global__ __launch_bounds__(1024)
void scan_inline(const float* __restrict__ mstate, const uint32_t* __restrict__ kb,
                 float* __restrict__ out) {
    const int r = blockIdx.x;
    const int tid = threadIdx.x;
    const int c0 = tid, c1 = tid + 1024;
    const int base = r * NCOL;
    float m0 = mstate[base + c0], m1 = mstate[base + c1];
    float z0 = 0.0f, z1 = 0.0f;
    __shared__ __align__(16) float red[2][16];
    const int lane = tid & 63, wid = tid >> 6;

    for (int t = 0; t < 1024; ++t) {
        uint32_t k0 = kb[2 * t], k1 = kb[2 * t + 1];
        float g0 = gumbel_from_bits(pbits32(k0, k1, (uint32_t)(base + c0)));
        float g1 = gumbel_from_bits(pbits32(k0, k1, (uint32_t)(base + c1)));
        float p0 = exp2f((m0 + g0) * C2);
        float p1 = exp2f((m1 + g1) * C2);
        float ws = wave_sum64(p0 + p1);
        if (lane == 0) red[t & 1][wid] = ws;
        __syncthreads();
        float S;
        {
            const float4* r4 = (const float4*)&red[t & 1][0];
            float4 v0 = r4[0], v1 = r4[1], v2 = r4[2], v3 = r4[3];
            S = ((v0.x + v0.y) + (v0.z + v0.w)) + ((v1.x + v1.y) + (v1.z + v1.w))
              + ((v2.x + v2.y) + (v2.z + v2.w)) + ((v3.x + v3.y) + (v3.z + v3.w));
        }
        float rs = __builtin_amdgcn_rcpf(S);
        m0 = p0 * rs; m1 = p1 * rs;
        z0 = fmaxf(z0, m0); z1 = fmaxf(z1, m1);
    }
    if (c0 < SPLIT) out[r * SPLIT + c0] = z0;
    else out[64 * SPLIT + r * (NCOL - SPLIT) + (c0 - SPLIT)] = z0;
    out[64 * SPLIT + r * (NCOL - SPLIT) + (c1 - SPLIT)] = z1;
}

// ---------------------------------------------------------------------------
// host
// ---------------------------------------------------------------------------
extern "C" void kernel_launch(void* const* d_in, const int* in_sizes, int n_in,
                              void* d_out, int out_size, void* d_ws, size_t ws_size,
                              hipStream_t stream) {
    const float* f   = (const float*)d_in[0];
    const float* W1  = (const float*)d_in[1];
    const float* b1  = (const float*)d_in[2];
    const float* g1  = (const float*)d_in[3];
    const float* be1 = (const float*)d_in[4];
    const float* rm1 = (const float*)d_in[5];
    const float* rv1 = (const float*)d_in[6];
    const float* W2  = (const float*)d_in[7];
    const float* b2  = (const float*)d_in[8];
    const float* g2  = (const float*)d_in[9];
    const float* be2 = (const float*)d_in[10];
    const float* rm2 = (const float*)d_in[11];
    const float* rv2 = (const float*)d_in[12];
    const float* W3  = (const float*)d_in[13];
    const float* b3  = (const float*)d_in[14];
    const float* rm3 = (const float*)d_in[15];
    const float* rv3 = (const float*)d_in[16];
    float* out = (float*)d_out;               // reference output dtype: float32

    float* ws = (float*)d_ws;
    size_t off = 0;
    auto alloc = [&](size_t n) { float* p = ws + off; off += n; return p; };

    uint32_t* keybuf = (uint32_t*)alloc(2048);
    float* s1 = alloc(8192); float* o1 = alloc(8192);
    float* s2 = alloc(8192); float* o2 = alloc(8192);
    float* x      = alloc(64 * 2048);
    float* h1     = alloc((size_t)64 * 8192);
    float* h2     = alloc((size_t)64 * 8192);
    float* mstate = alloc(NFLAT);
    float* zstate = alloc(NFLAT);
    size_t fixed = off;
    float* pbuf = ws + fixed;
    size_t region = (ws_size / 4 > fixed) ? (ws_size / 4 - fixed) : 0;

    const size_t HN = (size_t)64 * 8192;      // 524288
    const size_t GALL = (size_t)1024 * NFLAT; // 512 MiB of floats

    keygenF<<<dim3(4), 256, 0, stream>>>(keybuf);
    prep<<<dim3(32), 256, 0, stream>>>(b1, g1, be1, rm1, rv1,
                                       b2, g2, be2, rm2, rv2,
                                       s1, o1, s2, o2);
    fft_x<<<dim3(256), 256, 0, stream>>>(f, x);

    if (region >= GALL + 16 * HN) {
        // ============== BIG path ==========================================
        float* gbufAll = pbuf;
        float* parts   = pbuf + GALL;

        gemm_ks<false><<<dim3(64, 8), 256, 0, stream>>>(
            x, nullptr, nullptr, W1, parts, 2048, 256, 8192);
        combineP<<<dim3(2048), 256, 0, stream>>>(parts, h1, 8, (int)HN);
        gemm_ks<true><<<dim3(64, 16), 256, 0, stream>>>(
            h1, s1, o1, W2, parts, 8192, 512, 8192);
        combineP<<<dim3(2048), 256, 0, stream>>>(parts, h2, 16, (int)HN);
        gemm_ks<true><<<dim3(16, 16), 256, 0, stream>>>(
            h2, s2, o2, W3, parts, 8192, 512, 2048);
        combine3<<<dim3(512), 256, 0, stream>>>(parts, b3, rm3, rv3, mstate, 16);

        hash_chunk<<<dim3(256), 1024, 0, stream>>>(keybuf, gbufAll, 0, 128);
        for (int ch = 0; ch < 8; ++ch) {
            int hstart = (ch + 1) * 128;
            int hcnt = (hstart < 1024) ? 128 : 0;
            scan_fused<<<dim3(256), 1024, 0, stream>>>(
                mstate, zstate, gbufAll + (size_t)ch * 128 * NFLAT,
                gbufAll + (size_t)hstart * NFLAT, hstart, hcnt, keybuf,
                ch * 128, 128, (ch == 7) ? 1 : 0, out);
        }
    } else {
        // ============== SMALL path ========================================
        int KS1 = (region >= 8 * HN) ? 8 : (region >= 4 * HN) ? 4 :
                  (region >= 2 * HN) ? 2 : 1;
        int KS2 = (region >= 16 * HN) ? 16 : (region >= 8 * HN) ? 8 :
                  (region >= 4 * HN) ? 4 : (region >= 2 * HN) ? 2 : 1;
        int KS3 = (region >= 16 * (size_t)NFLAT) ? 16 :
                  (region >= 8 * (size_t)NFLAT) ? 8 :
                  (region >= 4 * (size_t)NFLAT) ? 4 :
                  (region >= 2 * (size_t)NFLAT) ? 2 : 1;
        int Tc = 0;
        const int cands[5] = {128, 64, 32, 16, 8};
        for (int ci = 0; ci < 5; ++ci)
            if (2 * (size_t)cands[ci] * NFLAT <= region) { Tc = cands[ci]; break; }

        gemm_ks<false><<<dim3(64, KS1), 256, 0, stream>>>(
            x, nullptr, nullptr, W1, (KS1 > 1) ? pbuf : h1, 2048, 2048 / KS1, 8192);
        if (KS1 > 1) combineP<<<dim3(2048), 256, 0, stream>>>(pbuf, h1, KS1, (int)HN);

        gemm_ks<true><<<dim3(64, KS2), 256, 0, stream>>>(
            h1, s1, o1, W2, (KS2 > 1) ? pbuf : h2, 8192, 8192 / KS2, 8192);
        if (KS2 > 1) combineP<<<dim3(2048), 256, 0, stream>>>(pbuf, h2, KS2, (int)HN);

        if (KS3 > 1) {
            gemm_ks<true><<<dim3(16, KS3), 256, 0, stream>>>(
                h2, s2, o2, W3, pbuf, 8192, 8192 / KS3, 2048);
            combine3<<<dim3(512), 256, 0, stream>>>(pbuf, b3, rm3, rv3, mstate, KS3);
        } else {
            gemm_ks<true><<<dim3(16, 1), 256, 0, stream>>>(
                h2, s2, o2, W3, h1, 8192, 8192, 2048);
            combine3<<<dim3(512), 256, 0, stream>>>(h1, b3, rm3, rv3, mstate, 1);
        }

        if (Tc > 0) {
            float* gbuf0 = pbuf;
            float* gbuf1 = pbuf + (size_t)Tc * NFLAT;
            int NC = 1024 / Tc;
            hash_chunk<<<dim3(256), 1024, 0, stream>>>(keybuf, gbuf0, 0, Tc);
            for (int ch = 0; ch < NC; ++ch) {
                float* ga = (ch & 1) ? gbuf1 : gbuf0;
                float* gb = (ch & 1) ? gbuf0 : gbuf1;
                int last = (ch == NC - 1) ? 1 : 0;
                scan_fused<<<dim3(256), 1024, 0, stream>>>(
                    mstate, zstate, ga, gb, (ch + 1) * Tc, last ? 0 : Tc,
                    keybuf, ch * Tc, Tc, last, out);
            }
        } else {
            scan_inline<<<dim3(64), 1024, 0, stream>>>(mstate, keybuf, out);
        }
    }
}